// Round 1
// baseline (30930.182 us; speedup 1.0000x reference)
//
#include <hip/hip_runtime.h>
#include <hip/hip_bf16.h>
#include <cstdint>

// GRU: T=512 steps, B=64, I=512, H=1024, O=512. fp32 throughout.
// Per step t:
//   phase A: r_t = sigmoid(h@W_rh + x@W_rx + b_r)   and   y_{t-1} = h@W_out^T + b_out
//   phase B: z_t = sigmoid(h@W_zh + x@W_zx + b_z); ht = tanh((h.r)@W_hh + x@W_hx + b_h)
//            h_t = h + z*(ht - h)
// Layouts: h, r, x all stored transposed [k][b] so the GEMM inner loop does
// coalesced float4 loads of 8 consecutive b. W_out pre-transposed to [k][o].

#define TT 512
#define BB 64
#define II 512
#define HH 1024
#define OO 512

typedef float4 f4;
__device__ __forceinline__ f4 ld4(const float* p){ return *reinterpret_cast<const f4*>(p); }

// ---------------- transposes (run once per call) ----------------
__global__ void k_transpose_x(const float* __restrict__ x, float* __restrict__ xT){
  // x[t][b][i] -> xT[t][i][b]
  size_t total = (size_t)TT * II * BB;
  for (size_t n = (size_t)blockIdx.x * blockDim.x + threadIdx.x; n < total;
       n += (size_t)gridDim.x * blockDim.x){
    size_t t = n / ((size_t)II * BB);
    size_t rem = n % ((size_t)II * BB);
    size_t i = rem / BB, b = rem % BB;
    xT[n] = x[(t * BB + b) * II + i];
  }
}

__global__ void k_transpose_wout(const float* __restrict__ W_out, float* __restrict__ WoT){
  // W_out[o][k] -> WoT[k][o]
  size_t total = (size_t)HH * OO;
  for (size_t n = (size_t)blockIdx.x * blockDim.x + threadIdx.x; n < total;
       n += (size_t)gridDim.x * blockDim.x){
    size_t k = n / OO, o = n % OO;
    WoT[n] = W_out[o * HH + k];
  }
}

__global__ void k_transpose_h0(const float* __restrict__ st, float* __restrict__ h0){
  // state[b][j] -> h0[j][b]
  size_t total = (size_t)HH * BB;
  for (size_t n = (size_t)blockIdx.x * blockDim.x + threadIdx.x; n < total;
       n += (size_t)gridDim.x * blockDim.x){
    size_t j = n / BB, b = n % BB;
    h0[n] = st[b * HH + j];
  }
}

// ---------------- phase A: r_t and y_{t-1} ----------------
// grid = 192 blocks x 256 threads.
//   blocks [0,128):  r.  block tile = [16 b x 32 j], K = 1024(h)+512(x), 32-way k-split
//   blocks [128,192): y. block tile = [16 b x 32 o], K = 1024
// thread: ksec = tid&31 (k-split), jg = (tid>>5)&3 (8 j each), bg = tid>>7 (8 b each)
// thread register tile 8b x 8j, k strided by 32.
__global__ __launch_bounds__(256) void k_phaseA(
    const float* __restrict__ xT, const float* __restrict__ hIn,
    const float* __restrict__ W_rh, const float* __restrict__ W_rx,
    const float* __restrict__ b_r,
    const float* __restrict__ WoT, const float* __restrict__ b_out,
    float* __restrict__ rT, float* __restrict__ Y, int t)
{
  const int tid  = threadIdx.x;
  const int ksec = tid & 31;
  const int jg   = (tid >> 5) & 3;
  const int bg   = tid >> 7;
  const int bid  = blockIdx.x;
  const bool isY = bid >= 128;
  if (!isY && t == TT) return;   // no r needed on the trailing y-only launch
  if ( isY && t == 0)  return;   // no y_{-1}

  int btile, jtile;
  if (!isY){ btile = bid >> 5;        jtile = bid & 31; }
  else     { int b2 = bid - 128; btile = b2 >> 4; jtile = b2 & 15; }
  const int b0 = btile * 16 + bg * 8;
  const int j0 = jtile * 32 + jg * 8;

  __shared__ float red[512][17];   // padded: stride 17 floats -> conflict-free

  float acc[8][8];
#pragma unroll
  for (int p = 0; p < 8; ++p)
#pragma unroll
    for (int q = 0; q < 8; ++q) acc[p][q] = 0.f;

  if (!isY){
    // ---- h part: k = ksec + 32*i, i in [0,32) ----
#pragma unroll 2
    for (int i = 0; i < 32; ++i){
      const int k = ksec + (i << 5);
      f4 h1 = ld4(hIn + k * BB + b0);
      f4 h2 = ld4(hIn + k * BB + b0 + 4);
      f4 w1 = ld4(W_rh + (size_t)k * HH + j0);
      f4 w2 = ld4(W_rh + (size_t)k * HH + j0 + 4);
      float hv[8] = {h1.x,h1.y,h1.z,h1.w,h2.x,h2.y,h2.z,h2.w};
      float wv[8] = {w1.x,w1.y,w1.z,w1.w,w2.x,w2.y,w2.z,w2.w};
#pragma unroll
      for (int p = 0; p < 8; ++p)
#pragma unroll
        for (int q = 0; q < 8; ++q) acc[p][q] = fmaf(hv[p], wv[q], acc[p][q]);
    }
    // ---- x part: kx = ksec + 32*i, i in [0,16) ----
    const float* xt = xT + (size_t)t * II * BB;
#pragma unroll 2
    for (int i = 0; i < 16; ++i){
      const int k = ksec + (i << 5);
      f4 h1 = ld4(xt + k * BB + b0);
      f4 h2 = ld4(xt + k * BB + b0 + 4);
      f4 w1 = ld4(W_rx + (size_t)k * HH + j0);
      f4 w2 = ld4(W_rx + (size_t)k * HH + j0 + 4);
      float hv[8] = {h1.x,h1.y,h1.z,h1.w,h2.x,h2.y,h2.z,h2.w};
      float wv[8] = {w1.x,w1.y,w1.z,w1.w,w2.x,w2.y,w2.z,w2.w};
#pragma unroll
      for (int p = 0; p < 8; ++p)
#pragma unroll
        for (int q = 0; q < 8; ++q) acc[p][q] = fmaf(hv[p], wv[q], acc[p][q]);
    }
  } else {
    // ---- y: K = 1024 over h only, weights WoT[k][o] ----
#pragma unroll 2
    for (int i = 0; i < 32; ++i){
      const int k = ksec + (i << 5);
      f4 h1 = ld4(hIn + k * BB + b0);
      f4 h2 = ld4(hIn + k * BB + b0 + 4);
      f4 w1 = ld4(WoT + (size_t)k * OO + j0);
      f4 w2 = ld4(WoT + (size_t)k * OO + j0 + 4);
      float hv[8] = {h1.x,h1.y,h1.z,h1.w,h2.x,h2.y,h2.z,h2.w};
      float wv[8] = {w1.x,w1.y,w1.z,w1.w,w2.x,w2.y,w2.z,w2.w};
#pragma unroll
      for (int p = 0; p < 8; ++p)
#pragma unroll
        for (int q = 0; q < 8; ++q) acc[p][q] = fmaf(hv[p], wv[q], acc[p][q]);
    }
  }

  // ---- k-split reduction: shfl halves 32 partials -> 16, LDS finishes ----
#pragma unroll
  for (int p = 0; p < 8; ++p)
#pragma unroll
    for (int q = 0; q < 8; ++q) acc[p][q] += __shfl_xor(acc[p][q], 16, 64);

  if (ksec < 16){
    const int bl = bg * 8, jl = jg * 8;
#pragma unroll
    for (int p = 0; p < 8; ++p)
#pragma unroll
      for (int q = 0; q < 8; ++q)
        red[(bl + p) * 32 + (jl + q)][ksec] = acc[p][q];
  }
  __syncthreads();

#pragma unroll
  for (int u = 0; u < 2; ++u){
    const int o = tid + u * 256;
    float s = 0.f;
#pragma unroll
    for (int r16 = 0; r16 < 16; ++r16) s += red[o][r16];
    const int bl = o >> 5, jl = o & 31;
    const int b = btile * 16 + bl;
    if (!isY){
      const int j = jtile * 32 + jl;
      const float v = s + b_r[j];
      rT[j * BB + b] = 1.f / (1.f + expf(-v));
    } else {
      const int oo = jtile * 32 + jl;
      Y[((size_t)(t - 1) * BB + b) * OO + oo] = s + b_out[oo];
    }
  }
}

// ---------------- phase B: z_t, ht, h update ----------------
// grid = 256 blocks x 256 threads. block tile = [16 b x 16 j] x {z, hh} gates.
// thread: ksec = tid&31, jg = (tid>>5)&3 (4 j each), bg = tid>>7 (8 b each)
// thread register tile 8b x 4j x 2 gates.
__global__ __launch_bounds__(256) void k_phaseB(
    const float* __restrict__ xT, const float* __restrict__ hIn,
    const float* __restrict__ rT,
    const float* __restrict__ W_zh, const float* __restrict__ W_zx,
    const float* __restrict__ b_z,
    const float* __restrict__ W_hh, const float* __restrict__ W_hx,
    const float* __restrict__ b_h,
    float* __restrict__ hOut, float* __restrict__ outTail, int t)
{
  const int tid  = threadIdx.x;
  const int ksec = tid & 31;
  const int jg   = (tid >> 5) & 3;
  const int bg   = tid >> 7;
  const int bid  = blockIdx.x;
  const int btile = bid >> 6;
  const int jtile = bid & 63;
  const int b0 = btile * 16 + bg * 8;
  const int j0 = jtile * 16 + jg * 4;

  __shared__ float red[512][17];

  float accZ[8][4], accH[8][4];
#pragma unroll
  for (int p = 0; p < 8; ++p)
#pragma unroll
    for (int q = 0; q < 4; ++q){ accZ[p][q] = 0.f; accH[p][q] = 0.f; }

  // ---- h part: z uses h, hh uses h*r ----
#pragma unroll 2
  for (int i = 0; i < 32; ++i){
    const int k = ksec + (i << 5);
    f4 h1 = ld4(hIn + k * BB + b0);
    f4 h2 = ld4(hIn + k * BB + b0 + 4);
    f4 r1 = ld4(rT  + k * BB + b0);
    f4 r2 = ld4(rT  + k * BB + b0 + 4);
    f4 wz = ld4(W_zh + (size_t)k * HH + j0);
    f4 wh = ld4(W_hh + (size_t)k * HH + j0);
    float hv[8] = {h1.x,h1.y,h1.z,h1.w,h2.x,h2.y,h2.z,h2.w};
    float rv[8] = {r1.x,r1.y,r1.z,r1.w,r2.x,r2.y,r2.z,r2.w};
    float wzv[4] = {wz.x,wz.y,wz.z,wz.w};
    float whv[4] = {wh.x,wh.y,wh.z,wh.w};
#pragma unroll
    for (int p = 0; p < 8; ++p){
      const float sv = hv[p] * rv[p];
#pragma unroll
      for (int q = 0; q < 4; ++q){
        accZ[p][q] = fmaf(hv[p], wzv[q], accZ[p][q]);
        accH[p][q] = fmaf(sv,   whv[q], accH[p][q]);
      }
    }
  }
  // ---- x part: both gates share x ----
  const float* xt = xT + (size_t)t * II * BB;
#pragma unroll 2
  for (int i = 0; i < 16; ++i){
    const int k = ksec + (i << 5);
    f4 x1 = ld4(xt + k * BB + b0);
    f4 x2 = ld4(xt + k * BB + b0 + 4);
    f4 wz = ld4(W_zx + (size_t)k * HH + j0);
    f4 wh = ld4(W_hx + (size_t)k * HH + j0);
    float xv[8] = {x1.x,x1.y,x1.z,x1.w,x2.x,x2.y,x2.z,x2.w};
    float wzv[4] = {wz.x,wz.y,wz.z,wz.w};
    float whv[4] = {wh.x,wh.y,wh.z,wh.w};
#pragma unroll
    for (int p = 0; p < 8; ++p)
#pragma unroll
      for (int q = 0; q < 4; ++q){
        accZ[p][q] = fmaf(xv[p], wzv[q], accZ[p][q]);
        accH[p][q] = fmaf(xv[p], whv[q], accH[p][q]);
      }
  }

  // ---- reduction ----
#pragma unroll
  for (int p = 0; p < 8; ++p)
#pragma unroll
    for (int q = 0; q < 4; ++q){
      accZ[p][q] += __shfl_xor(accZ[p][q], 16, 64);
      accH[p][q] += __shfl_xor(accH[p][q], 16, 64);
    }
  if (ksec < 16){
    const int bl = bg * 8, jl = jg * 4;
#pragma unroll
    for (int p = 0; p < 8; ++p)
#pragma unroll
      for (int q = 0; q < 4; ++q){
        red[(bl + p) * 16 + (jl + q)][ksec]       = accZ[p][q];
        red[256 + (bl + p) * 16 + (jl + q)][ksec] = accH[p][q];
      }
  }
  __syncthreads();

  float sZ = 0.f, sH = 0.f;
#pragma unroll
  for (int r16 = 0; r16 < 16; ++r16){
    sZ += red[tid][r16];
    sH += red[tid + 256][r16];
  }
  const int bl = tid >> 4, jl = tid & 15;
  const int b = btile * 16 + bl;
  const int j = jtile * 16 + jl;
  const float z  = 1.f / (1.f + expf(-(sZ + b_z[j])));
  const float ht = tanhf(sH + b_h[j]);
  const float hold = hIn[j * BB + b];
  const float hnew = hold + z * (ht - hold);
  hOut[j * BB + b] = hnew;
  if (t == TT - 1) outTail[b * HH + j] = hnew;
}

// ---------------- host ----------------
extern "C" void kernel_launch(void* const* d_in, const int* in_sizes, int n_in,
                              void* d_out, int out_size, void* d_ws, size_t ws_size,
                              hipStream_t stream) {
  const float* x     = (const float*)d_in[0];
  const float* st    = (const float*)d_in[1];
  const float* W_zh  = (const float*)d_in[2];
  const float* W_zx  = (const float*)d_in[3];
  const float* b_z   = (const float*)d_in[4];
  const float* W_rh  = (const float*)d_in[5];
  const float* W_rx  = (const float*)d_in[6];
  const float* b_r   = (const float*)d_in[7];
  const float* W_hh  = (const float*)d_in[8];
  const float* W_hx  = (const float*)d_in[9];
  const float* b_h   = (const float*)d_in[10];
  const float* W_out = (const float*)d_in[11];
  const float* b_out = (const float*)d_in[12];
  float* out = (float*)d_out;
  float* ws  = (float*)d_ws;

  const size_t xT_sz  = (size_t)TT * II * BB;   // 16,777,216
  const size_t WoT_sz = (size_t)HH * OO;        //    524,288
  const size_t h_sz   = (size_t)HH * BB;        //     65,536
  const size_t need_bytes = (xT_sz + WoT_sz + 3 * h_sz) * sizeof(float); // ~67 MB
  if (ws_size < need_bytes) return;  // workspace too small; fail loudly via validation

  float* xT   = ws;
  float* WoT  = xT + xT_sz;
  float* hbuf = WoT + WoT_sz;        // two buffers, parity-indexed
  float* rT   = hbuf + 2 * h_sz;

  k_transpose_x   <<<8192, 256, 0, stream>>>(x, xT);
  k_transpose_wout<<< 512, 256, 0, stream>>>(W_out, WoT);
  k_transpose_h0  <<<  64, 256, 0, stream>>>(st, hbuf);

  float* Ytail = out + (size_t)TT * BB * OO;   // h_final [B][H]

  for (int t = 0; t <= TT; ++t){
    const float* hIn = hbuf + (size_t)(t & 1) * h_sz;
    float*       hOut = hbuf + (size_t)((t + 1) & 1) * h_sz;
    // phase A: r_t (t<T) and y_{t-1} (t>0)
    k_phaseA<<<192, 256, 0, stream>>>(xT, hIn, W_rh, W_rx, b_r, WoT, b_out, rT, out, t);
    // phase B: z_t, ht, h_t (t<T)
    if (t < TT)
      k_phaseB<<<256, 256, 0, stream>>>(xT, hIn, rT, W_zh, W_zx, b_z,
                                        W_hh, W_hx, b_h, hOut, Ytail, t);
  }
}

// Round 2
// 26887.274 us; speedup vs baseline: 1.1504x; 1.1504x over previous
//
#include <hip/hip_runtime.h>
#include <cstdint>

// GRU persistent-kernel: T=512, B=64, I=512, H=1024, O=512, fp32.
// One block per CU (forced by 95 KB LDS). Block bid owns j-cols {4bid..4bid+3}
// of W_zh/W_rh/W_hh/W_zx/W_rx/W_hx and o-cols {2bid,2bid+1} of W_out, all held
// in XOR-swizzled LDS for the whole scan. Grid barrier = 16-leaf + root
// device-scope atomic counters in ws, 2 barriers/step; barrier A is split
// (arrive after s written, wait after z/y computed) to hide its latency.
//
// Per step t:
//   A1: r = sigmoid(h@W_rh + x_t@W_rx + b_r); s = r*h   -> arrive(A)
//   A2: z = sigmoid(h@W_zh + x_t@W_zx + b_z) (to LDS); y_{t-1} = h@W_out^T + b_out
//       -> wait(A)
//   B : ht = tanh(s@W_hh + x_t@W_hx + b_h); h = h + z*(ht-h)  -> arrive+wait(B)
// Trailing pass: y_511.

#define TT 512
#define BB 64
#define II 512
#define HH 1024
#define OO 512
#define NBLK 256
#define NTHR 512

// LDS float-index layout
#define ZH   0          // 4 x 1024
#define RH   4096
#define HHB  8192
#define ZX   12288      // 4 x 512
#define RX   14336
#define HX   16384
#define WO   18432      // 2 x 1024
#define WTOT 20480
#define RSTR 385        // reduction row stride (385 % 32 == 1 -> bank spread)

typedef float4 f4;
__device__ __forceinline__ f4 ld4(const float* p){ return *reinterpret_cast<const f4*>(p); }
// swizzle byte-bits[4:6] (float-idx bits[2:4]) with k's row index -> conflict-free
// ds_read_b128 when lanes differ in ksec (stride 128 B).
__device__ __forceinline__ int swzk(int k){ return k ^ (((k >> 5) & 7) << 2); }

#define LOADG4(dst, base, off) { f4 v_ = ld4((base) + (off)); \
  dst[0]=v_.x; dst[1]=v_.y; dst[2]=v_.z; dst[3]=v_.w; }
#define LOADW4(dst, fidx) { f4 v_ = *reinterpret_cast<const f4*>(&sW[(fidx)]); \
  dst[0]=v_.x; dst[1]=v_.y; dst[2]=v_.z; dst[3]=v_.w; }

// ---------------- one-time transposes ----------------
__global__ void k_transpose_x(const float* __restrict__ x, float* __restrict__ xT){
  // x[t][b][i] -> xT[t][i][b]
  size_t total = (size_t)TT * II * BB;
  for (size_t n = (size_t)blockIdx.x * blockDim.x + threadIdx.x; n < total;
       n += (size_t)gridDim.x * blockDim.x){
    size_t t = n / ((size_t)II * BB);
    size_t rem = n % ((size_t)II * BB);
    size_t i = rem / BB, b = rem % BB;
    xT[n] = x[(t * BB + b) * II + i];
  }
}

__global__ void k_transpose_h0(const float* __restrict__ st, float* __restrict__ h0){
  // state[b][j] -> h0[j][b]
  size_t total = (size_t)HH * BB;
  for (size_t n = (size_t)blockIdx.x * blockDim.x + threadIdx.x; n < total;
       n += (size_t)gridDim.x * blockDim.x){
    size_t j = n / BB, b = n % BB;
    h0[n] = st[b * HH + j];
  }
}

__global__ void k_init_bars(unsigned* bars){
  if (threadIdx.x < 320) bars[threadIdx.x] = 0;
}

// ---------------- barrier helpers ----------------
__device__ __forceinline__ void bar_arrive(unsigned* bars, int bid, unsigned ep){
  __threadfence();  // cache-wide wb: block's s/h writes visible device-scope
  unsigned* leaf = bars + (bid & 15) * 16;   // 64B-spaced leaves
  unsigned old = __hip_atomic_fetch_add(leaf, 1u, __ATOMIC_ACQ_REL, __HIP_MEMORY_SCOPE_AGENT);
  if (old + 1u == ep * 16u)
    __hip_atomic_fetch_add(bars + 256, 1u, __ATOMIC_ACQ_REL, __HIP_MEMORY_SCOPE_AGENT);
}
__device__ __forceinline__ void bar_wait(unsigned* bars, unsigned ep){
  while (__hip_atomic_load(bars + 256, __ATOMIC_ACQUIRE, __HIP_MEMORY_SCOPE_AGENT) < ep * 16u)
    __builtin_amdgcn_s_sleep(2);
}

// ---------------- the persistent GRU kernel ----------------
__global__ __launch_bounds__(NTHR, 2) void k_gru(
    const float* __restrict__ xT,
    float* __restrict__ h,          // [H][B], pre-initialized to state^T
    float* __restrict__ s,          // [H][B]
    const float* __restrict__ W_zh, const float* __restrict__ W_zx, const float* __restrict__ b_z,
    const float* __restrict__ W_rh, const float* __restrict__ W_rx, const float* __restrict__ b_r,
    const float* __restrict__ W_hh, const float* __restrict__ W_hx, const float* __restrict__ b_h,
    const float* __restrict__ W_out, const float* __restrict__ b_out,
    float* __restrict__ out, unsigned* __restrict__ bars)
{
  __shared__ float sW[WTOT];          // 80 KB weights (swizzled)
  __shared__ float red[8 * RSTR];     // 12 KB cross-wave reduction
  __shared__ float sZ[256];           // z gate (4 j x 64 b), block-local

  const int tid = threadIdx.x;
  const int bid = blockIdx.x;

  // ---- prologue: gather weight slices into swizzled LDS ----
  {
    const int jg = bid * 4;
    #pragma unroll
    for (int kk2 = 0; kk2 < 2; ++kk2){
      const int k = tid * 2 + kk2;          // 0..1023
      f4 vz = ld4(W_zh + (size_t)k * HH + jg);
      f4 vr = ld4(W_rh + (size_t)k * HH + jg);
      f4 vh = ld4(W_hh + (size_t)k * HH + jg);
      const int kx = swzk(k);
      float az[4] = {vz.x,vz.y,vz.z,vz.w};
      float ar[4] = {vr.x,vr.y,vr.z,vr.w};
      float ah[4] = {vh.x,vh.y,vh.z,vh.w};
      #pragma unroll
      for (int c = 0; c < 4; ++c){
        sW[ZH  + c*1024 + kx] = az[c];
        sW[RH  + c*1024 + kx] = ar[c];
        sW[HHB + c*1024 + kx] = ah[c];
      }
    }
    {
      const int k = tid;                    // 0..511
      f4 vz = ld4(W_zx + (size_t)k * HH + jg);
      f4 vr = ld4(W_rx + (size_t)k * HH + jg);
      f4 vh = ld4(W_hx + (size_t)k * HH + jg);
      const int kx = swzk(k);
      float az[4] = {vz.x,vz.y,vz.z,vz.w};
      float ar[4] = {vr.x,vr.y,vr.z,vr.w};
      float ah[4] = {vh.x,vh.y,vh.z,vh.w};
      #pragma unroll
      for (int c = 0; c < 4; ++c){
        sW[ZX + c*512 + kx] = az[c];
        sW[RX + c*512 + kx] = ar[c];
        sW[HX + c*512 + kx] = ah[c];
      }
    }
    {
      const int oc = tid >> 8;              // 0..1
      const int k0 = (tid & 255) * 4;       // 0..1020
      f4 v = ld4(W_out + (size_t)(bid*2 + oc) * HH + k0);
      float a[4] = {v.x,v.y,v.z,v.w};
      #pragma unroll
      for (int kk = 0; kk < 4; ++kk)
        sW[WO + oc*1024 + swzk(k0 + kk)] = a[kk];
    }
  }
  __syncthreads();

  const int bgroup = tid & 15, b0 = bgroup * 4;
  const int ksec   = tid >> 4;          // 0..31
  const int wv     = tid >> 6;          // wave 0..7
  const bool redwr = ((ksec & 3) == 0); // lanes 0-15 of each wave
  const int kb_h = ksec * 32;           // K=1024 split 32-way
  const int kb_x = ksec * 16;           // K=512 split 32-way
  const float* hb = h + kb_h * BB + b0;
  const float* sb = s + kb_h * BB + b0;

  for (int t = 0; t < TT; ++t){
    const float* xb = xT + (size_t)t * II * BB + kb_x * BB + b0;

    // ======== A1: r gate ========
    float aR[4][4] = {};
    #pragma unroll 2
    for (int i = 0; i < 8; ++i){
      const int kx = swzk(kb_h + i*4);
      float hv[4][4];
      #pragma unroll
      for (int kk = 0; kk < 4; ++kk) LOADG4(hv[kk], hb, i*256 + kk*64);
      #pragma unroll
      for (int c = 0; c < 4; ++c){
        float wf[4]; LOADW4(wf, RH + c*1024 + kx);
        #pragma unroll
        for (int kk = 0; kk < 4; ++kk)
          #pragma unroll
          for (int bb = 0; bb < 4; ++bb)
            aR[c][bb] = fmaf(wf[kk], hv[kk][bb], aR[c][bb]);
      }
    }
    #pragma unroll 2
    for (int i = 0; i < 4; ++i){
      const int kx = swzk(kb_x + i*4);
      float xv[4][4];
      #pragma unroll
      for (int kk = 0; kk < 4; ++kk) LOADG4(xv[kk], xb, i*256 + kk*64);
      #pragma unroll
      for (int c = 0; c < 4; ++c){
        float wf[4]; LOADW4(wf, RX + c*512 + kx);
        #pragma unroll
        for (int kk = 0; kk < 4; ++kk)
          #pragma unroll
          for (int bb = 0; bb < 4; ++bb)
            aR[c][bb] = fmaf(wf[kk], xv[kk][bb], aR[c][bb]);
      }
    }
    #pragma unroll
    for (int c = 0; c < 4; ++c)
      #pragma unroll
      for (int bb = 0; bb < 4; ++bb){
        aR[c][bb] += __shfl_xor(aR[c][bb], 16);
        aR[c][bb] += __shfl_xor(aR[c][bb], 32);
      }
    if (redwr)
      #pragma unroll
      for (int c = 0; c < 4; ++c)
        #pragma unroll
        for (int bb = 0; bb < 4; ++bb)
          red[wv*RSTR + c*64 + b0 + bb] = aR[c][bb];
    __syncthreads();
    if (tid < 256){
      float sum = 0.f;
      #pragma unroll
      for (int w = 0; w < 8; ++w) sum += red[w*RSTR + tid];
      const int c = tid >> 6, b = tid & 63, jg = bid*4 + c;
      const float rv = 1.f / (1.f + expf(-(sum + b_r[jg])));
      s[jg*BB + b] = rv * h[jg*BB + b];
    }
    __syncthreads();                       // s written; red free for A2
    if (tid == 0) bar_arrive(bars, bid, 2*t + 1);   // split barrier: arrive only

    // ======== A2: z gate + y_{t-1} (overlaps barrier A latency) ========
    float aZ[4][4] = {};
    float aY[2][4] = {};
    #pragma unroll 2
    for (int i = 0; i < 8; ++i){
      const int kx = swzk(kb_h + i*4);
      float hv[4][4];
      #pragma unroll
      for (int kk = 0; kk < 4; ++kk) LOADG4(hv[kk], hb, i*256 + kk*64);
      #pragma unroll
      for (int c = 0; c < 4; ++c){
        float wf[4]; LOADW4(wf, ZH + c*1024 + kx);
        #pragma unroll
        for (int kk = 0; kk < 4; ++kk)
          #pragma unroll
          for (int bb = 0; bb < 4; ++bb)
            aZ[c][bb] = fmaf(wf[kk], hv[kk][bb], aZ[c][bb]);
      }
      #pragma unroll
      for (int c = 0; c < 2; ++c){
        float wf[4]; LOADW4(wf, WO + c*1024 + kx);
        #pragma unroll
        for (int kk = 0; kk < 4; ++kk)
          #pragma unroll
          for (int bb = 0; bb < 4; ++bb)
            aY[c][bb] = fmaf(wf[kk], hv[kk][bb], aY[c][bb]);
      }
    }
    #pragma unroll 2
    for (int i = 0; i < 4; ++i){
      const int kx = swzk(kb_x + i*4);
      float xv[4][4];
      #pragma unroll
      for (int kk = 0; kk < 4; ++kk) LOADG4(xv[kk], xb, i*256 + kk*64);
      #pragma unroll
      for (int c = 0; c < 4; ++c){
        float wf[4]; LOADW4(wf, ZX + c*512 + kx);
        #pragma unroll
        for (int kk = 0; kk < 4; ++kk)
          #pragma unroll
          for (int bb = 0; bb < 4; ++bb)
            aZ[c][bb] = fmaf(wf[kk], xv[kk][bb], aZ[c][bb]);
      }
    }
    #pragma unroll
    for (int c = 0; c < 4; ++c)
      #pragma unroll
      for (int bb = 0; bb < 4; ++bb){
        aZ[c][bb] += __shfl_xor(aZ[c][bb], 16);
        aZ[c][bb] += __shfl_xor(aZ[c][bb], 32);
      }
    #pragma unroll
    for (int c = 0; c < 2; ++c)
      #pragma unroll
      for (int bb = 0; bb < 4; ++bb){
        aY[c][bb] += __shfl_xor(aY[c][bb], 16);
        aY[c][bb] += __shfl_xor(aY[c][bb], 32);
      }
    if (redwr){
      #pragma unroll
      for (int c = 0; c < 4; ++c)
        #pragma unroll
        for (int bb = 0; bb < 4; ++bb)
          red[wv*RSTR + c*64 + b0 + bb] = aZ[c][bb];
      #pragma unroll
      for (int c = 0; c < 2; ++c)
        #pragma unroll
        for (int bb = 0; bb < 4; ++bb)
          red[wv*RSTR + 256 + c*64 + b0 + bb] = aY[c][bb];
    }
    __syncthreads();
    if (tid < 256){
      float sum = 0.f;
      #pragma unroll
      for (int w = 0; w < 8; ++w) sum += red[w*RSTR + tid];
      const int c = tid >> 6, jg = bid*4 + c;
      sZ[tid] = 1.f / (1.f + expf(-(sum + b_z[jg])));
    } else if (tid < 384){
      const int o2 = tid - 256;
      float sum = 0.f;
      #pragma unroll
      for (int w = 0; w < 8; ++w) sum += red[w*RSTR + tid];
      const int oc = o2 >> 6, b = o2 & 63, og = bid*2 + oc;
      if (t > 0) out[((size_t)(t-1)*BB + b)*OO + og] = sum + b_out[og];
    }
    if (tid == 0) bar_wait(bars, 2*t + 1);          // split barrier: wait
    __syncthreads();

    // ======== B: candidate + h update ========
    float aH[4][4] = {};
    #pragma unroll 2
    for (int i = 0; i < 8; ++i){
      const int kx = swzk(kb_h + i*4);
      float sv[4][4];
      #pragma unroll
      for (int kk = 0; kk < 4; ++kk) LOADG4(sv[kk], sb, i*256 + kk*64);
      #pragma unroll
      for (int c = 0; c < 4; ++c){
        float wf[4]; LOADW4(wf, HHB + c*1024 + kx);
        #pragma unroll
        for (int kk = 0; kk < 4; ++kk)
          #pragma unroll
          for (int bb = 0; bb < 4; ++bb)
            aH[c][bb] = fmaf(wf[kk], sv[kk][bb], aH[c][bb]);
      }
    }
    #pragma unroll 2
    for (int i = 0; i < 4; ++i){
      const int kx = swzk(kb_x + i*4);
      float xv[4][4];
      #pragma unroll
      for (int kk = 0; kk < 4; ++kk) LOADG4(xv[kk], xb, i*256 + kk*64);
      #pragma unroll
      for (int c = 0; c < 4; ++c){
        float wf[4]; LOADW4(wf, HX + c*512 + kx);
        #pragma unroll
        for (int kk = 0; kk < 4; ++kk)
          #pragma unroll
          for (int bb = 0; bb < 4; ++bb)
            aH[c][bb] = fmaf(wf[kk], xv[kk][bb], aH[c][bb]);
      }
    }
    #pragma unroll
    for (int c = 0; c < 4; ++c)
      #pragma unroll
      for (int bb = 0; bb < 4; ++bb){
        aH[c][bb] += __shfl_xor(aH[c][bb], 16);
        aH[c][bb] += __shfl_xor(aH[c][bb], 32);
      }
    if (redwr)
      #pragma unroll
      for (int c = 0; c < 4; ++c)
        #pragma unroll
        for (int bb = 0; bb < 4; ++bb)
          red[wv*RSTR + c*64 + b0 + bb] = aH[c][bb];
    __syncthreads();
    if (tid < 256){
      float sum = 0.f;
      #pragma unroll
      for (int w = 0; w < 8; ++w) sum += red[w*RSTR + tid];
      const int c = tid >> 6, b = tid & 63, jg = bid*4 + c;
      const float ht = tanhf(sum + b_h[jg]);
      const float z  = sZ[tid];
      const float hold = h[jg*BB + b];
      const float hnew = fmaf(z, ht - hold, hold);
      h[jg*BB + b] = hnew;
      if (t == TT - 1) out[(size_t)TT*BB*OO + (size_t)b*HH + jg] = hnew;
    }
    __syncthreads();                       // h written; red free
    if (tid == 0){ bar_arrive(bars, bid, 2*t + 2); bar_wait(bars, 2*t + 2); }
    __syncthreads();
  }

  // ======== trailing y_{T-1} ========
  {
    float aY[2][4] = {};
    #pragma unroll 2
    for (int i = 0; i < 8; ++i){
      const int kx = swzk(kb_h + i*4);
      float hv[4][4];
      #pragma unroll
      for (int kk = 0; kk < 4; ++kk) LOADG4(hv[kk], hb, i*256 + kk*64);
      #pragma unroll
      for (int c = 0; c < 2; ++c){
        float wf[4]; LOADW4(wf, WO + c*1024 + kx);
        #pragma unroll
        for (int kk = 0; kk < 4; ++kk)
          #pragma unroll
          for (int bb = 0; bb < 4; ++bb)
            aY[c][bb] = fmaf(wf[kk], hv[kk][bb], aY[c][bb]);
      }
    }
    #pragma unroll
    for (int c = 0; c < 2; ++c)
      #pragma unroll
      for (int bb = 0; bb < 4; ++bb){
        aY[c][bb] += __shfl_xor(aY[c][bb], 16);
        aY[c][bb] += __shfl_xor(aY[c][bb], 32);
      }
    if (redwr)
      #pragma unroll
      for (int c = 0; c < 2; ++c)
        #pragma unroll
        for (int bb = 0; bb < 4; ++bb)
          red[wv*RSTR + c*64 + b0 + bb] = aY[c][bb];
    __syncthreads();
    if (tid < 128){
      float sum = 0.f;
      #pragma unroll
      for (int w = 0; w < 8; ++w) sum += red[w*RSTR + tid];
      const int oc = tid >> 6, b = tid & 63, og = bid*2 + oc;
      out[((size_t)(TT-1)*BB + b)*OO + og] = sum + b_out[og];
    }
  }
}

// ---------------- host ----------------
extern "C" void kernel_launch(void* const* d_in, const int* in_sizes, int n_in,
                              void* d_out, int out_size, void* d_ws, size_t ws_size,
                              hipStream_t stream) {
  const float* x     = (const float*)d_in[0];
  const float* st    = (const float*)d_in[1];
  const float* W_zh  = (const float*)d_in[2];
  const float* W_zx  = (const float*)d_in[3];
  const float* b_z   = (const float*)d_in[4];
  const float* W_rh  = (const float*)d_in[5];
  const float* W_rx  = (const float*)d_in[6];
  const float* b_r   = (const float*)d_in[7];
  const float* W_hh  = (const float*)d_in[8];
  const float* W_hx  = (const float*)d_in[9];
  const float* b_h   = (const float*)d_in[10];
  const float* W_out = (const float*)d_in[11];
  const float* b_out = (const float*)d_in[12];
  float* out = (float*)d_out;
  float* ws  = (float*)d_ws;

  const size_t xT_sz = (size_t)TT * II * BB;     // 16,777,216
  const size_t h_sz  = (size_t)HH * BB;          // 65,536
  const size_t need  = (xT_sz + 2*h_sz) * sizeof(float) + 320*sizeof(unsigned);
  if (ws_size < need) return;

  float* xT = ws;
  float* h  = xT + xT_sz;
  float* s  = h + h_sz;
  unsigned* bars = (unsigned*)(s + h_sz);

  k_transpose_x <<<8192, 256, 0, stream>>>(x, xT);
  k_transpose_h0<<<  64, 256, 0, stream>>>(st, h);
  k_init_bars   <<<   1, 512, 0, stream>>>(bars);

  k_gru<<<NBLK, NTHR, 0, stream>>>(xT, h, s,
                                   W_zh, W_zx, b_z, W_rh, W_rx, b_r,
                                   W_hh, W_hx, b_h, W_out, b_out, out, bars);
}

// Round 3
// 19699.738 us; speedup vs baseline: 1.5701x; 1.3649x over previous
//
#include <hip/hip_runtime.h>
#include <cstdint>

// GRU persistent kernel v3: T=512, B=64, I=512, H=1024, O=512, fp32.
// Grid 256 = 128 j-tiles x 2 batch-halves. Block owns 8 j-cols x 32 b.
// h-gate weights (W_rh/W_zh/W_hh j-slices, 96 KB) live in swizzled LDS.
// x-gate weights pre-transposed [j][k], streamed. W_out streamed raw.
// Two independent barrier groups (one per batch-half), relaxed-spin +
// single acquire fence. Phase order per step:
//   A : r = sigmoid(h@W_rh + xr_pre + b_r); s = r*h        -> arrive(A)
//   A2: z = sigmoid(h@W_zh + xz_pre + b_z); y_{t-1}=h@Wout -> wait(A)
//   B : ht = tanh(s@W_hh + xh_pre + b_h); h += z*(ht-h)    -> arrive(B)
//   C : xr/xz/xh_pre for step t+1 (x only, hides barrier B) -> wait(B)

#define TT 512
#define BB 64
#define II 512
#define HH 1024
#define OO 512

typedef float4 f4;
__device__ __forceinline__ f4 ld4(const float* p){ return *reinterpret_cast<const f4*>(p); }
// k-swizzle for ksec-stride-16 LDS weight reads: XOR word bits [2:4] with k bits [4:6]
__device__ __forceinline__ int swz(int k){ return k ^ (((k >> 4) & 7) << 2); }

// ---------------- one-time prep kernels ----------------
__global__ void k_transpose_x(const float* __restrict__ x, float* __restrict__ xT){
  // x[t][b][i] -> xT[t][i][b]
  size_t total = (size_t)TT * II * BB;
  for (size_t n = (size_t)blockIdx.x * blockDim.x + threadIdx.x; n < total;
       n += (size_t)gridDim.x * blockDim.x){
    size_t t = n / ((size_t)II * BB);
    size_t rem = n % ((size_t)II * BB);
    size_t i = rem / BB, b = rem % BB;
    xT[n] = x[(t * BB + b) * II + i];
  }
}

__global__ void k_transpose_wx(const float* __restrict__ W, float* __restrict__ WT){
  // W[k][j] (I x H) -> WT[j][k] (H x I)
  size_t n = (size_t)blockIdx.x * blockDim.x + threadIdx.x;
  if (n >= (size_t)II * HH) return;
  size_t j = n / II, k = n % II;
  WT[n] = W[k * HH + j];
}

__global__ void k_transpose_h0(const float* __restrict__ st, float* __restrict__ h0){
  // state[b][j] -> h0[j][b]
  size_t n = (size_t)blockIdx.x * blockDim.x + threadIdx.x;
  if (n >= (size_t)HH * BB) return;
  size_t j = n / BB, b = n % BB;
  h0[n] = st[b * HH + j];
}

__global__ void k_init_bars(unsigned* bars){
  if (threadIdx.x < 512) bars[threadIdx.x] = 0;
}

// ---------------- barrier (per batch-half group of 128 blocks) ----------------
// leaves: 8 per group, 16 arrivals each per epoch; root +1 per completed leaf.
__device__ __forceinline__ void g_arrive(unsigned* bars, int g, int jt, unsigned ep){
  __builtin_amdgcn_fence(__ATOMIC_RELEASE, "agent");
  unsigned* leaf = bars + (g * 9 + (jt & 7)) * 16;
  unsigned old = __hip_atomic_fetch_add(leaf, 1u, __ATOMIC_RELAXED, __HIP_MEMORY_SCOPE_AGENT);
  if (old + 1u == ep * 16u)
    __hip_atomic_fetch_add(bars + (g * 9 + 8) * 16, 1u, __ATOMIC_RELAXED, __HIP_MEMORY_SCOPE_AGENT);
}
__device__ __forceinline__ void g_wait(unsigned* bars, int g, unsigned ep){
  unsigned* root = bars + (g * 9 + 8) * 16;
  while (__hip_atomic_load(root, __ATOMIC_RELAXED, __HIP_MEMORY_SCOPE_AGENT) < ep * 8u)
    __builtin_amdgcn_s_sleep(1);
  __builtin_amdgcn_fence(__ATOMIC_ACQUIRE, "agent");
}

// shfl-reduce over the 3 ksec bits that live inside a wave (lanes 8,16,32)
#define WREDUCE(v) { v += __shfl_xor(v, 8); v += __shfl_xor(v, 16); v += __shfl_xor(v, 32); }

// ---------------- the persistent GRU kernel ----------------
__global__ __launch_bounds__(512, 2) void k_gru(
    const float* __restrict__ xT,
    const float* __restrict__ WxTr, const float* __restrict__ WxTz, const float* __restrict__ WxTh,
    float* __restrict__ h, float* __restrict__ s,
    const float* __restrict__ W_zh, const float* __restrict__ b_z,
    const float* __restrict__ W_rh, const float* __restrict__ b_r,
    const float* __restrict__ W_hh, const float* __restrict__ b_h,
    const float* __restrict__ W_out, const float* __restrict__ b_out,
    float* __restrict__ out, unsigned* __restrict__ bars)
{
  __shared__ float sW[3 * 8 * 1024];   // [g:0=RH,1=ZH,2=HH][c<8][k swz]  96 KB
  __shared__ float red[8 * 528];       // cross-wave reduce, 2x256 slots  16.5 KB
  __shared__ float xpre[3][256];       // x-projections for current step
  __shared__ float sZ[256];            // z gate
  __shared__ float sBias[32];          // b_r[8] b_z[8] b_h[8] b_out[4]

  const int tid = threadIdx.x;
  const int bid = blockIdx.x;
  const int jt = bid & 127, bhalf = bid >> 7;
  const int j0 = jt * 8, o0 = jt * 4, bbase = bhalf * 32;

  // ---- prologue: weight slices -> swizzled LDS ----
  #pragma unroll
  for (int kk = 0; kk < 2; ++kk){
    const int k = tid * 2 + kk;            // 0..1023
    f4 vr = ld4(W_rh + (size_t)k * HH + j0);
    f4 vr2 = ld4(W_rh + (size_t)k * HH + j0 + 4);
    f4 vz = ld4(W_zh + (size_t)k * HH + j0);
    f4 vz2 = ld4(W_zh + (size_t)k * HH + j0 + 4);
    f4 vh = ld4(W_hh + (size_t)k * HH + j0);
    f4 vh2 = ld4(W_hh + (size_t)k * HH + j0 + 4);
    const int kx = swz(k);
    float ar[8] = {vr.x,vr.y,vr.z,vr.w,vr2.x,vr2.y,vr2.z,vr2.w};
    float az[8] = {vz.x,vz.y,vz.z,vz.w,vz2.x,vz2.y,vz2.z,vz2.w};
    float ah[8] = {vh.x,vh.y,vh.z,vh.w,vh2.x,vh2.y,vh2.z,vh2.w};
    #pragma unroll
    for (int c = 0; c < 8; ++c){
      sW[0*8192 + c*1024 + kx] = ar[c];
      sW[1*8192 + c*1024 + kx] = az[c];
      sW[2*8192 + c*1024 + kx] = ah[c];
    }
  }
  if (tid < 8){
    sBias[tid]      = b_r[j0 + tid];
    sBias[8 + tid]  = b_z[j0 + tid];
    sBias[16 + tid] = b_h[j0 + tid];
    if (tid < 4) sBias[24 + tid] = b_out[o0 + tid];
  }

  const int bg = tid & 7, b0 = bbase + bg * 4;
  const int ksec = tid >> 3;           // 0..63
  const int wv = tid >> 6;             // wave 0..7
  const bool wr0 = ((tid & 56) == 0);  // in-wave ksec bits == 0
  const int kh0 = ksec * 16;           // K=1024 / 64
  const int kx0 = ksec * 8;            // K=512  / 64
  __syncthreads();

  for (int t = -1; t < TT; ++t){
    f4 st4[16];                        // h stash, A -> A2
    if (t >= 0){
      // ================= A: r gate =================
      float aR[8][4] = {};
      const float* hb = h + kh0 * BB + b0;
      #pragma unroll
      for (int i4 = 0; i4 < 4; ++i4){
        #pragma unroll
        for (int kk = 0; kk < 4; ++kk) st4[i4*4+kk] = ld4(hb + (i4*4+kk) * BB);
        const int kxc = swz(kh0 + i4*4);
        #pragma unroll
        for (int c = 0; c < 8; ++c){
          f4 wf = *reinterpret_cast<const f4*>(&sW[0*8192 + c*1024 + kxc]);
          float wvv[4] = {wf.x, wf.y, wf.z, wf.w};
          #pragma unroll
          for (int kk = 0; kk < 4; ++kk){
            const f4 hv = st4[i4*4+kk];
            aR[c][0] = fmaf(wvv[kk], hv.x, aR[c][0]);
            aR[c][1] = fmaf(wvv[kk], hv.y, aR[c][1]);
            aR[c][2] = fmaf(wvv[kk], hv.z, aR[c][2]);
            aR[c][3] = fmaf(wvv[kk], hv.w, aR[c][3]);
          }
        }
      }
      #pragma unroll
      for (int c = 0; c < 8; ++c)
        #pragma unroll
        for (int bb = 0; bb < 4; ++bb) WREDUCE(aR[c][bb]);
      if (wr0)
        #pragma unroll
        for (int c = 0; c < 8; ++c)
          #pragma unroll
          for (int bb = 0; bb < 4; ++bb)
            red[wv*528 + c*32 + bg*4 + bb] = aR[c][bb];
      __syncthreads();
      if (tid < 256){
        float sum = 0.f;
        #pragma unroll
        for (int w = 0; w < 8; ++w) sum += red[w*528 + tid];
        const int c = tid >> 5, bl = tid & 31;
        const float v = sum + xpre[0][tid] + sBias[c];
        const float rr = 1.f / (1.f + expf(-v));
        const int jg = j0 + c, bgl = bbase + bl;
        s[jg*BB + bgl] = rr * h[jg*BB + bgl];
      }
      __syncthreads();                       // s stores drained (vmcnt) at barrier
      if (tid == 0) g_arrive(bars, bhalf, jt, 2*t + 1);

      // ================= A2: z gate + y_{t-1} (hides barrier A) =================
      float aZ[8][4] = {};
      float aY[4][4] = {};
      #pragma unroll
      for (int i4 = 0; i4 < 4; ++i4){
        const int kc = kh0 + i4*4;
        const int kxc = swz(kc);
        #pragma unroll
        for (int c = 0; c < 8; ++c){
          f4 wf = *reinterpret_cast<const f4*>(&sW[1*8192 + c*1024 + kxc]);
          float wvv[4] = {wf.x, wf.y, wf.z, wf.w};
          #pragma unroll
          for (int kk = 0; kk < 4; ++kk){
            const f4 hv = st4[i4*4+kk];
            aZ[c][0] = fmaf(wvv[kk], hv.x, aZ[c][0]);
            aZ[c][1] = fmaf(wvv[kk], hv.y, aZ[c][1]);
            aZ[c][2] = fmaf(wvv[kk], hv.z, aZ[c][2]);
            aZ[c][3] = fmaf(wvv[kk], hv.w, aZ[c][3]);
          }
        }
        #pragma unroll
        for (int oc = 0; oc < 4; ++oc){
          f4 wo = ld4(W_out + (size_t)(o0 + oc) * HH + kc);
          float wvv[4] = {wo.x, wo.y, wo.z, wo.w};
          #pragma unroll
          for (int kk = 0; kk < 4; ++kk){
            const f4 hv = st4[i4*4+kk];
            aY[oc][0] = fmaf(wvv[kk], hv.x, aY[oc][0]);
            aY[oc][1] = fmaf(wvv[kk], hv.y, aY[oc][1]);
            aY[oc][2] = fmaf(wvv[kk], hv.z, aY[oc][2]);
            aY[oc][3] = fmaf(wvv[kk], hv.w, aY[oc][3]);
          }
        }
      }
      #pragma unroll
      for (int c = 0; c < 8; ++c)
        #pragma unroll
        for (int bb = 0; bb < 4; ++bb) WREDUCE(aZ[c][bb]);
      #pragma unroll
      for (int oc = 0; oc < 4; ++oc)
        #pragma unroll
        for (int bb = 0; bb < 4; ++bb) WREDUCE(aY[oc][bb]);
      if (wr0){
        #pragma unroll
        for (int c = 0; c < 8; ++c)
          #pragma unroll
          for (int bb = 0; bb < 4; ++bb)
            red[wv*528 + c*32 + bg*4 + bb] = aZ[c][bb];
        #pragma unroll
        for (int oc = 0; oc < 4; ++oc)
          #pragma unroll
          for (int bb = 0; bb < 4; ++bb)
            red[wv*528 + 256 + oc*32 + bg*4 + bb] = aY[oc][bb];
      }
      __syncthreads();
      if (tid < 256){
        float sum = 0.f;
        #pragma unroll
        for (int w = 0; w < 8; ++w) sum += red[w*528 + tid];
        const int c = tid >> 5;
        sZ[tid] = 1.f / (1.f + expf(-(sum + xpre[1][tid] + sBias[8 + c])));
      } else if (tid < 384){
        const int idx = tid - 256;
        float sum = 0.f;
        #pragma unroll
        for (int w = 0; w < 8; ++w) sum += red[w*528 + tid];
        const int oc = idx >> 5, bl = idx & 31;
        if (t > 0)
          out[((size_t)(t-1)*BB + bbase + bl)*OO + o0 + oc] = sum + sBias[24 + oc];
      }
      if (tid == 0) g_wait(bars, bhalf, 2*t + 1);
      __syncthreads();

      // ================= B: candidate + h update =================
      float aH[8][4] = {};
      const float* sb = s + kh0 * BB + b0;
      #pragma unroll
      for (int i4 = 0; i4 < 4; ++i4){
        f4 sv4[4];
        #pragma unroll
        for (int kk = 0; kk < 4; ++kk) sv4[kk] = ld4(sb + (i4*4+kk) * BB);
        const int kxc = swz(kh0 + i4*4);
        #pragma unroll
        for (int c = 0; c < 8; ++c){
          f4 wf = *reinterpret_cast<const f4*>(&sW[2*8192 + c*1024 + kxc]);
          float wvv[4] = {wf.x, wf.y, wf.z, wf.w};
          #pragma unroll
          for (int kk = 0; kk < 4; ++kk){
            aH[c][0] = fmaf(wvv[kk], sv4[kk].x, aH[c][0]);
            aH[c][1] = fmaf(wvv[kk], sv4[kk].y, aH[c][1]);
            aH[c][2] = fmaf(wvv[kk], sv4[kk].z, aH[c][2]);
            aH[c][3] = fmaf(wvv[kk], sv4[kk].w, aH[c][3]);
          }
        }
      }
      #pragma unroll
      for (int c = 0; c < 8; ++c)
        #pragma unroll
        for (int bb = 0; bb < 4; ++bb) WREDUCE(aH[c][bb]);
      if (wr0)
        #pragma unroll
        for (int c = 0; c < 8; ++c)
          #pragma unroll
          for (int bb = 0; bb < 4; ++bb)
            red[wv*528 + c*32 + bg*4 + bb] = aH[c][bb];
      __syncthreads();
      if (tid < 256){
        float sum = 0.f;
        #pragma unroll
        for (int w = 0; w < 8; ++w) sum += red[w*528 + tid];
        const int c = tid >> 5, bl = tid & 31;
        const int jg = j0 + c, bgl = bbase + bl;
        const float ht = tanhf(sum + xpre[2][tid] + sBias[16 + c]);
        const float z = sZ[tid];
        const float hold = h[jg*BB + bgl];
        const float hnew = fmaf(z, ht - hold, hold);
        h[jg*BB + bgl] = hnew;
        if (t == TT - 1) out[(size_t)TT*BB*OO + (size_t)bgl*HH + jg] = hnew;
      }
      __syncthreads();
      if (tid == 0) g_arrive(bars, bhalf, jt, 2*t + 2);
    }

    // ================= C: x-projections for step t+1 (hides barrier B) ===========
    if (t + 1 < TT){
      const int tc = t + 1;
      float aXr[8][4] = {}, aXz[8][4] = {}, aXh[8][4] = {};
      const float* xb = xT + (size_t)tc * II * BB + kx0 * BB + b0;
      #pragma unroll
      for (int i4 = 0; i4 < 2; ++i4){
        f4 xv4[4];
        #pragma unroll
        for (int kk = 0; kk < 4; ++kk) xv4[kk] = ld4(xb + (i4*4+kk) * BB);
        #pragma unroll
        for (int c = 0; c < 8; ++c){
          f4 wr_ = ld4(WxTr + (size_t)(j0 + c) * II + kx0 + i4*4);
          f4 wz_ = ld4(WxTz + (size_t)(j0 + c) * II + kx0 + i4*4);
          f4 wh_ = ld4(WxTh + (size_t)(j0 + c) * II + kx0 + i4*4);
          float wrv[4] = {wr_.x, wr_.y, wr_.z, wr_.w};
          float wzv[4] = {wz_.x, wz_.y, wz_.z, wz_.w};
          float whv[4] = {wh_.x, wh_.y, wh_.z, wh_.w};
          #pragma unroll
          for (int kk = 0; kk < 4; ++kk){
            const f4 xv = xv4[kk];
            aXr[c][0] = fmaf(wrv[kk], xv.x, aXr[c][0]);
            aXr[c][1] = fmaf(wrv[kk], xv.y, aXr[c][1]);
            aXr[c][2] = fmaf(wrv[kk], xv.z, aXr[c][2]);
            aXr[c][3] = fmaf(wrv[kk], xv.w, aXr[c][3]);
            aXz[c][0] = fmaf(wzv[kk], xv.x, aXz[c][0]);
            aXz[c][1] = fmaf(wzv[kk], xv.y, aXz[c][1]);
            aXz[c][2] = fmaf(wzv[kk], xv.z, aXz[c][2]);
            aXz[c][3] = fmaf(wzv[kk], xv.w, aXz[c][3]);
            aXh[c][0] = fmaf(whv[kk], xv.x, aXh[c][0]);
            aXh[c][1] = fmaf(whv[kk], xv.y, aXh[c][1]);
            aXh[c][2] = fmaf(whv[kk], xv.z, aXh[c][2]);
            aXh[c][3] = fmaf(whv[kk], xv.w, aXh[c][3]);
          }
        }
      }
      #pragma unroll
      for (int c = 0; c < 8; ++c)
        #pragma unroll
        for (int bb = 0; bb < 4; ++bb){ WREDUCE(aXr[c][bb]); WREDUCE(aXz[c][bb]); WREDUCE(aXh[c][bb]); }
      if (wr0)
        #pragma unroll
        for (int c = 0; c < 8; ++c)
          #pragma unroll
          for (int bb = 0; bb < 4; ++bb){
            red[wv*528 + c*32 + bg*4 + bb]       = aXr[c][bb];
            red[wv*528 + 256 + c*32 + bg*4 + bb] = aXz[c][bb];
          }
      __syncthreads();
      {
        float sum = 0.f;
        #pragma unroll
        for (int w = 0; w < 8; ++w) sum += red[w*528 + tid];
        if (tid < 256) xpre[0][tid] = sum;
        else           xpre[1][tid - 256] = sum;   // tid 256..511 maps to slots 256..511
      }
      __syncthreads();
      if (wr0)
        #pragma unroll
        for (int c = 0; c < 8; ++c)
          #pragma unroll
          for (int bb = 0; bb < 4; ++bb)
            red[wv*528 + c*32 + bg*4 + bb] = aXh[c][bb];
      __syncthreads();
      if (tid < 256){
        float sum = 0.f;
        #pragma unroll
        for (int w = 0; w < 8; ++w) sum += red[w*528 + tid];
        xpre[2][tid] = sum;
      }
      __syncthreads();
    }

    if (t >= 0){
      if (tid == 0) g_wait(bars, bhalf, 2*t + 2);
      __syncthreads();
    }
  }

  // ================= trailing y_{T-1} from final h =================
  {
    float aY[4][4] = {};
    const float* hb = h + kh0 * BB + b0;
    #pragma unroll
    for (int i4 = 0; i4 < 4; ++i4){
      f4 hv4[4];
      #pragma unroll
      for (int kk = 0; kk < 4; ++kk) hv4[kk] = ld4(hb + (i4*4+kk) * BB);
      const int kc = kh0 + i4*4;
      #pragma unroll
      for (int oc = 0; oc < 4; ++oc){
        f4 wo = ld4(W_out + (size_t)(o0 + oc) * HH + kc);
        float wvv[4] = {wo.x, wo.y, wo.z, wo.w};
        #pragma unroll
        for (int kk = 0; kk < 4; ++kk){
          aY[oc][0] = fmaf(wvv[kk], hv4[kk].x, aY[oc][0]);
          aY[oc][1] = fmaf(wvv[kk], hv4[kk].y, aY[oc][1]);
          aY[oc][2] = fmaf(wvv[kk], hv4[kk].z, aY[oc][2]);
          aY[oc][3] = fmaf(wvv[kk], hv4[kk].w, aY[oc][3]);
        }
      }
    }
    #pragma unroll
    for (int oc = 0; oc < 4; ++oc)
      #pragma unroll
      for (int bb = 0; bb < 4; ++bb) WREDUCE(aY[oc][bb]);
    if (wr0)
      #pragma unroll
      for (int oc = 0; oc < 4; ++oc)
        #pragma unroll
        for (int bb = 0; bb < 4; ++bb)
          red[wv*528 + oc*32 + bg*4 + bb] = aY[oc][bb];
    __syncthreads();
    if (tid < 128){
      float sum = 0.f;
      #pragma unroll
      for (int w = 0; w < 8; ++w) sum += red[w*528 + tid];
      const int oc = tid >> 5, bl = tid & 31;
      out[((size_t)(TT-1)*BB + bbase + bl)*OO + o0 + oc] = sum + sBias[24 + oc];
    }
  }
}

// ---------------- host ----------------
extern "C" void kernel_launch(void* const* d_in, const int* in_sizes, int n_in,
                              void* d_out, int out_size, void* d_ws, size_t ws_size,
                              hipStream_t stream) {
  const float* x     = (const float*)d_in[0];
  const float* st    = (const float*)d_in[1];
  const float* W_zh  = (const float*)d_in[2];
  const float* W_zx  = (const float*)d_in[3];
  const float* b_z   = (const float*)d_in[4];
  const float* W_rh  = (const float*)d_in[5];
  const float* W_rx  = (const float*)d_in[6];
  const float* b_r   = (const float*)d_in[7];
  const float* W_hh  = (const float*)d_in[8];
  const float* W_hx  = (const float*)d_in[9];
  const float* b_h   = (const float*)d_in[10];
  const float* W_out = (const float*)d_in[11];
  const float* b_out = (const float*)d_in[12];
  float* out = (float*)d_out;
  float* ws  = (float*)d_ws;

  const size_t xT_sz = (size_t)TT * II * BB;   // 16,777,216
  const size_t wx_sz = (size_t)II * HH;        //    524,288
  const size_t h_sz  = (size_t)HH * BB;        //     65,536
  const size_t need  = (xT_sz + 3*wx_sz + 2*h_sz) * sizeof(float) + 512*sizeof(unsigned);
  if (ws_size < need) return;

  float* xT   = ws;
  float* WxTr = xT + xT_sz;
  float* WxTz = WxTr + wx_sz;
  float* WxTh = WxTz + wx_sz;
  float* h    = WxTh + wx_sz;
  float* s    = h + h_sz;
  unsigned* bars = (unsigned*)(s + h_sz);

  k_transpose_x <<<8192, 256, 0, stream>>>(x, xT);
  k_transpose_wx<<<2048, 256, 0, stream>>>(W_rx, WxTr);
  k_transpose_wx<<<2048, 256, 0, stream>>>(W_zx, WxTz);
  k_transpose_wx<<<2048, 256, 0, stream>>>(W_hx, WxTh);
  k_transpose_h0<<< 256, 256, 0, stream>>>(st, h);
  k_init_bars   <<<   1, 512, 0, stream>>>(bars);

  k_gru<<<256, 512, 0, stream>>>(xT, WxTr, WxTz, WxTh, h, s,
                                 W_zh, b_z, W_rh, b_r, W_hh, b_h,
                                 W_out, b_out, out, bars);
}